// Round 2
// baseline (275.337 us; speedup 1.0000x reference)
//
#include <hip/hip_runtime.h>

#define NSAMPLE 32
#define RX 0.1f
#define RY 0.1f
#define RZ 0.1f

// One wave (64 lanes) per query point.
// Phase 1: ordered cooperative scan of the query's batch slice of xyz,
//          collecting the first NSAMPLE in-cube point indices (ballot+prefix).
// Phase 2: coalesced gather of feature rows into LDS (lane = channel),
//          then coalesced transposed store to (C, NSAMPLE) layout.
__global__ __launch_bounds__(64) void cube_query_group_kernel(
    const float* __restrict__ xyz,        // (N,3)
    const int*   __restrict__ xyz_cnt,    // (B,)
    const float* __restrict__ new_xyz,    // (M,3)
    const int*   __restrict__ new_cnt,    // (B,)
    const float* __restrict__ features,   // (N,C)
    float* __restrict__ out_grouped,      // (M,C,NSAMPLE)
    float* __restrict__ out_cnt,          // (M,)
    int B, int M, int C)
{
    const int q = blockIdx.x;
    if (q >= M) return;
    const int lane = threadIdx.x;   // 0..63

    // ---- locate batch of this query and its xyz slice ----
    int b = 0;
    int xstart = 0;
    {
        int acc = 0;
        for (int i = 0; i < B; ++i) {
            int cnt = new_cnt[i];
            if (q < acc + cnt) { b = i; break; }
            acc += cnt;
        }
        for (int i = 0; i < b; ++i) xstart += xyz_cnt[i];
    }
    const int nb = xyz_cnt[b];

    const float qx = new_xyz[q * 3 + 0];
    const float qy = new_xyz[q * 3 + 1];
    const float qz = new_xyz[q * 3 + 2];

    __shared__ int   s_idx[NSAMPLE];
    __shared__ float s_feat[NSAMPLE][65];   // +1 pad: 65 mod 32 = 1 -> conflict-free transpose read

    // ---- Phase 1: ordered scan, first NSAMPLE in-cube points ----
    int found = 0;
    for (int base = 0; base < nb && found < NSAMPLE; base += 64) {
        const int p = base + lane;
        bool incube = false;
        if (p < nb) {
            const int gp = xstart + p;
            const float dx = qx - xyz[gp * 3 + 0];
            const float dy = qy - xyz[gp * 3 + 1];
            const float dz = qz - xyz[gp * 3 + 2];
            incube = (fabsf(dx) < RX) && (fabsf(dy) < RY) && (fabsf(dz) < RZ);
        }
        const unsigned long long mask = __ballot(incube);
        if (incube) {
            const int prefix = __popcll(mask & ((1ull << lane) - 1ull));
            const int slot = found + prefix;
            if (slot < NSAMPLE) s_idx[slot] = xstart + p;
        }
        found += __popcll(mask);
    }
    if (found > NSAMPLE) found = NSAMPLE;
    __syncthreads();

    // ---- Phase 2: gather feature rows into LDS (coalesced: lane = channel) ----
    #pragma unroll
    for (int s = 0; s < NSAMPLE; ++s) {
        float v = 0.0f;
        if (s < found && lane < C) {
            v = features[(size_t)s_idx[s] * C + lane];
        }
        s_feat[s][lane] = v;
    }
    __syncthreads();

    // ---- transposed store: out[q, c, s], thread t = c*NSAMPLE + s ----
    float* og = out_grouped + (size_t)q * C * NSAMPLE;
    const int total = C * NSAMPLE;             // 2048 for C=64
    for (int t = lane; t < total; t += 64) {
        const int c = t >> 5;                  // t / NSAMPLE
        const int s = t & (NSAMPLE - 1);       // t % NSAMPLE
        og[t] = s_feat[s][c];
    }

    if (lane == 0) out_cnt[q] = (float)found;
}

extern "C" void kernel_launch(void* const* d_in, const int* in_sizes, int n_in,
                              void* d_out, int out_size, void* d_ws, size_t ws_size,
                              hipStream_t stream) {
    const float* xyz      = (const float*)d_in[0];
    const int*   xyz_cnt  = (const int*)d_in[1];
    const float* new_xyz  = (const float*)d_in[2];
    const int*   new_cnt  = (const int*)d_in[3];
    const float* features = (const float*)d_in[4];

    const int B = in_sizes[1];
    const int N = in_sizes[0] / 3;
    const int M = in_sizes[2] / 3;
    const int C = in_sizes[4] / N;   // 64

    float* out_grouped = (float*)d_out;                       // M*C*NSAMPLE
    float* out_cnt     = (float*)d_out + (size_t)M * C * NSAMPLE;

    dim3 grid(M), block(64);
    hipLaunchKernelGGL(cube_query_group_kernel, grid, block, 0, stream,
                       xyz, xyz_cnt, new_xyz, new_cnt, features,
                       out_grouped, out_cnt, B, M, C);
}

// Round 3
// 123.930 us; speedup vs baseline: 2.2217x; 2.2217x over previous
//
#include <hip/hip_runtime.h>

#define NSAMPLE 32
#define RX 0.1f
#define RY 0.1f
#define RZ 0.1f
#define WPB 4   // waves per block, one query per wave

// One wave (64 lanes) per query.
// Scan: 128 points/iter (2 per lane), depth-1 prefetch, ballot+prefix slot
//       assignment preserving point-index order, early exit at 32 found.
// Epilogue: direct global gather -> coalesced float4 stores, no LDS staging.
//   out[q][c][s]: lane owns rows s0..s0+3 (s0 = 4*(lane&7)) and channel
//   c = 8k + (lane>>3) for k=0..7; each store writes out[t0..t0+3],
//   t0 = (k*64+lane)*4  ->  c = t0>>5, s = t0&31 matches (c, s0..s0+3).
__global__ __launch_bounds__(64 * WPB, 8) void cube_query_group_kernel(
    const float* __restrict__ xyz,        // (N,3)
    const int*   __restrict__ xyz_cnt,    // (B,)
    const float* __restrict__ new_xyz,    // (M,3)
    const int*   __restrict__ new_cnt,    // (B,)
    const float* __restrict__ features,   // (N,C) C=64
    float* __restrict__ out_grouped,      // (M,C,NSAMPLE)
    float* __restrict__ out_cnt,          // (M,)
    int B, int M, int C)
{
    const int wave = threadIdx.x >> 6;
    const int lane = threadIdx.x & 63;
    const int q = blockIdx.x * WPB + wave;
    if (q >= M) return;

    __shared__ int s_idx_all[WPB][NSAMPLE];
    int* s_idx = s_idx_all[wave];
    if (lane < NSAMPLE) s_idx[lane] = 0;   // safe gather target for empty slots

    // ---- locate batch of this query and its xyz slice (B is tiny) ----
    int b = 0, qacc = 0, xstart = 0;
    for (int i = 0; i < B; ++i) {
        const int cnt = new_cnt[i];
        if (q < qacc + cnt) { b = i; break; }
        qacc += cnt;
        xstart += xyz_cnt[i];
    }
    const int nb = xyz_cnt[b];

    const float qx = new_xyz[q * 3 + 0];
    const float qy = new_xyz[q * 3 + 1];
    const float qz = new_xyz[q * 3 + 2];
    const float* __restrict__ xp = xyz + (size_t)xstart * 3;

    // ---- ordered scan: first NSAMPLE in-cube points, 128 pts/iter ----
    int found = 0;
    int base = 0;

    float ax, ay, az, bx, by, bz;       // current chunk (2 points/lane)
    {
        const int p0 = lane < nb ? lane : nb - 1;
        const int p1 = (lane + 64) < nb ? (lane + 64) : nb - 1;
        ax = xp[p0 * 3 + 0]; ay = xp[p0 * 3 + 1]; az = xp[p0 * 3 + 2];
        bx = xp[p1 * 3 + 0]; by = xp[p1 * 3 + 1]; bz = xp[p1 * 3 + 2];
    }

    while (true) {
        const int nbase = base + 128;
        float nax = 0.f, nay = 0.f, naz = 0.f, nbx = 0.f, nby = 0.f, nbz = 0.f;
        if (nbase < nb) {   // wave-uniform prefetch of next chunk
            const int p0 = (nbase + lane) < nb ? (nbase + lane) : nb - 1;
            const int p1 = (nbase + 64 + lane) < nb ? (nbase + 64 + lane) : nb - 1;
            nax = xp[p0 * 3 + 0]; nay = xp[p0 * 3 + 1]; naz = xp[p0 * 3 + 2];
            nbx = xp[p1 * 3 + 0]; nby = xp[p1 * 3 + 1]; nbz = xp[p1 * 3 + 2];
        }

        const bool c0 = (base + lane < nb) &&
                        (fabsf(qx - ax) < RX) && (fabsf(qy - ay) < RY) && (fabsf(qz - az) < RZ);
        const bool c1 = (base + 64 + lane < nb) &&
                        (fabsf(qx - bx) < RX) && (fabsf(qy - by) < RY) && (fabsf(qz - bz) < RZ);

        const unsigned long long m0 = __ballot(c0);
        const unsigned long long m1 = __ballot(c1);
        const unsigned long long lt = (1ull << lane) - 1ull;

        if (c0) {
            const int slot = found + __popcll(m0 & lt);
            if (slot < NSAMPLE) s_idx[slot] = xstart + base + lane;
        }
        const int f0 = found + __popcll(m0);
        if (c1) {
            const int slot = f0 + __popcll(m1 & lt);
            if (slot < NSAMPLE) s_idx[slot] = xstart + base + 64 + lane;
        }
        found = f0 + __popcll(m1);

        base = nbase;
        if (found >= NSAMPLE || base >= nb) break;
        ax = nax; ay = nay; az = naz; bx = nbx; by = nby; bz = nbz;
    }
    if (found > NSAMPLE) found = NSAMPLE;

    // all lanes' ds_writes must land before cross-lane ds_reads (single wave,
    // no barrier needed; fence the LDS queue + pin the schedule)
    asm volatile("s_waitcnt lgkmcnt(0)" ::: "memory");
    __builtin_amdgcn_sched_barrier(0);

    // ---- direct gather + coalesced float4 stores ----
    const int s0  = 4 * (lane & 7);      // this lane's 4 sample rows
    const int chi = lane >> 3;           // channel sub-index
    const int r0 = s_idx[s0 + 0];
    const int r1 = s_idx[s0 + 1];
    const int r2 = s_idx[s0 + 2];
    const int r3 = s_idx[s0 + 3];
    const float k0 = (s0 + 0) < found ? 1.0f : 0.0f;
    const float k1 = (s0 + 1) < found ? 1.0f : 0.0f;
    const float k2 = (s0 + 2) < found ? 1.0f : 0.0f;
    const float k3 = (s0 + 3) < found ? 1.0f : 0.0f;

    const float* __restrict__ f0p = features + (size_t)r0 * C;
    const float* __restrict__ f1p = features + (size_t)r1 * C;
    const float* __restrict__ f2p = features + (size_t)r2 * C;
    const float* __restrict__ f3p = features + (size_t)r3 * C;

    float* __restrict__ og = out_grouped + (size_t)q * (C * NSAMPLE);
    #pragma unroll
    for (int k = 0; k < 8; ++k) {
        const int c = 8 * k + chi;
        float4 v;
        v.x = f0p[c] * k0;
        v.y = f1p[c] * k1;
        v.z = f2p[c] * k2;
        v.w = f3p[c] * k3;
        *reinterpret_cast<float4*>(og + (size_t)(k * 64 + lane) * 4) = v;
    }

    if (lane == 0) out_cnt[q] = (float)found;
}

extern "C" void kernel_launch(void* const* d_in, const int* in_sizes, int n_in,
                              void* d_out, int out_size, void* d_ws, size_t ws_size,
                              hipStream_t stream) {
    const float* xyz      = (const float*)d_in[0];
    const int*   xyz_cnt  = (const int*)d_in[1];
    const float* new_xyz  = (const float*)d_in[2];
    const int*   new_cnt  = (const int*)d_in[3];
    const float* features = (const float*)d_in[4];

    const int B = in_sizes[1];
    const int N = in_sizes[0] / 3;
    const int M = in_sizes[2] / 3;
    const int C = in_sizes[4] / N;   // 64

    float* out_grouped = (float*)d_out;
    float* out_cnt     = (float*)d_out + (size_t)M * C * NSAMPLE;

    dim3 grid((M + WPB - 1) / WPB), block(64 * WPB);
    hipLaunchKernelGGL(cube_query_group_kernel, grid, block, 0, stream,
                       xyz, xyz_cnt, new_xyz, new_cnt, features,
                       out_grouped, out_cnt, B, M, C);
}

// Round 4
// 105.835 us; speedup vs baseline: 2.6016x; 1.1710x over previous
//
#include <hip/hip_runtime.h>

#define NSAMPLE 32
#define RX 0.1f
#define RY 0.1f
#define RZ 0.1f
#define WPB 4   // waves per block, one query per wave

// Pre-pass: pack xyz (N,3) AoS -> float4 (x,y,z,0) so the scan loop does one
// aligned dwordx4 load per point with offset-immediate addressing.
__global__ __launch_bounds__(256) void pack_xyz_kernel(
    const float* __restrict__ xyz, float4* __restrict__ xyz4, int N)
{
    const int i = blockIdx.x * blockDim.x + threadIdx.x;
    if (i < N) {
        float4 v;
        v.x = xyz[i * 3 + 0];
        v.y = xyz[i * 3 + 1];
        v.z = xyz[i * 3 + 2];
        v.w = 0.0f;
        xyz4[i] = v;
    }
}

// One wave (64 lanes) per query.
// Scan: 256 points/iter (4 float4 loads/lane), depth-1 prefetch, clamp-free
//       fast loop over the multiple-of-256 prefix + masked tail. Ballot+prefix
//       slot assignment preserves point-index order; early exit at 32 found.
// Epilogue: direct global gather (32B-coalesced) -> perfect float4 stores.
template <bool PACKED>
__global__ __launch_bounds__(64 * WPB, 8) void cube_query_group_kernel(
    const float*  __restrict__ xyz,       // (N,3) AoS (used when !PACKED)
    const float4* __restrict__ xyz4,      // (N) packed (used when PACKED)
    const int*    __restrict__ xyz_cnt,   // (B,)
    const float*  __restrict__ new_xyz,   // (M,3)
    const int*    __restrict__ new_cnt,   // (B,)
    const float*  __restrict__ features,  // (N,C) C=64
    float* __restrict__ out_grouped,      // (M,C,NSAMPLE)
    float* __restrict__ out_cnt,          // (M,)
    int B, int M, int C)
{
    const int wave = threadIdx.x >> 6;
    const int lane = threadIdx.x & 63;
    const int q = blockIdx.x * WPB + wave;
    if (q >= M) return;

    __shared__ int s_idx_all[WPB][NSAMPLE];
    int* s_idx = s_idx_all[wave];
    if (lane < NSAMPLE) s_idx[lane] = 0;   // safe gather target for empty slots

    // ---- locate batch of this query and its xyz slice (B is tiny) ----
    int b = 0, qacc = 0, xstart = 0;
    for (int i = 0; i < B; ++i) {
        const int cnt = new_cnt[i];
        if (q < qacc + cnt) { b = i; break; }
        qacc += cnt;
        xstart += xyz_cnt[i];
    }
    const int nb = xyz_cnt[b];

    const float qx = new_xyz[q * 3 + 0];
    const float qy = new_xyz[q * 3 + 1];
    const float qz = new_xyz[q * 3 + 2];

    const float4* __restrict__ xp4 = PACKED ? (xyz4 + xstart) : nullptr;
    const float*  __restrict__ xp  = PACKED ? nullptr : (xyz + (size_t)xstart * 3);

    auto load_pt = [&](int p) -> float4 {
        if (PACKED) return xp4[p];
        float4 v;
        v.x = xp[p * 3 + 0]; v.y = xp[p * 3 + 1]; v.z = xp[p * 3 + 2]; v.w = 0.f;
        return v;
    };

    const unsigned long long lt = (1ull << lane) - 1ull;
    int found = 0;
    int base = 0;
    const int nfull = nb & ~255;   // clamp-free prefix (multiple of 256)

    if (nfull >= 256) {
        float4 cur[4];
        #pragma unroll
        for (int k = 0; k < 4; ++k) cur[k] = load_pt(k * 64 + lane);

        while (true) {
            const int nbase = base + 256;
            const bool have_next = (nbase < nfull);    // wave-uniform
            float4 nxt[4];
            if (have_next) {
                #pragma unroll
                for (int k = 0; k < 4; ++k) nxt[k] = load_pt(nbase + k * 64 + lane);
            }

            #pragma unroll
            for (int k = 0; k < 4; ++k) {
                const bool c = (fabsf(qx - cur[k].x) < RX) &
                               (fabsf(qy - cur[k].y) < RY) &
                               (fabsf(qz - cur[k].z) < RZ);
                const unsigned long long m = __ballot(c);
                if (c) {
                    const int slot = found + __popcll(m & lt);
                    if (slot < NSAMPLE) s_idx[slot] = xstart + base + k * 64 + lane;
                }
                found += __popcll(m);
            }

            base = nbase;
            if (found >= NSAMPLE || !have_next) break;
            #pragma unroll
            for (int k = 0; k < 4; ++k) cur[k] = nxt[k];
        }
    }

    // masked tail (nb not a multiple of 256, or tiny nb)
    while (found < NSAMPLE && base < nb) {
        #pragma unroll
        for (int k = 0; k < 4; ++k) {
            const int p = base + k * 64 + lane;
            const bool inb = (p < nb);
            const float4 v = load_pt(inb ? p : 0);
            const bool c = inb &
                           (fabsf(qx - v.x) < RX) &
                           (fabsf(qy - v.y) < RY) &
                           (fabsf(qz - v.z) < RZ);
            const unsigned long long m = __ballot(c);
            if (c) {
                const int slot = found + __popcll(m & lt);
                if (slot < NSAMPLE) s_idx[slot] = xstart + p;
            }
            found += __popcll(m);
        }
        base += 256;
    }
    if (found > NSAMPLE) found = NSAMPLE;

    // all lanes' ds_writes must land before cross-lane reads (single wave:
    // fence the LDS queue + pin the schedule; no barrier needed)
    asm volatile("s_waitcnt lgkmcnt(0)" ::: "memory");
    __builtin_amdgcn_sched_barrier(0);

    // ---- direct gather + coalesced float4 stores ----
    // lane owns rows s0..s0+3 (s0 = 4*(lane&7)) and channels c = 8k + (lane>>3).
    // For fixed k, lanes {j, j+8, .., j+56} read row_j channels 8k..8k+7
    // = 32 contiguous bytes -> 8 x 32B requests per load instruction.
    const int s0  = 4 * (lane & 7);
    const int chi = lane >> 3;
    const int r0 = s_idx[s0 + 0];
    const int r1 = s_idx[s0 + 1];
    const int r2 = s_idx[s0 + 2];
    const int r3 = s_idx[s0 + 3];
    const float k0 = (s0 + 0) < found ? 1.0f : 0.0f;
    const float k1 = (s0 + 1) < found ? 1.0f : 0.0f;
    const float k2 = (s0 + 2) < found ? 1.0f : 0.0f;
    const float k3 = (s0 + 3) < found ? 1.0f : 0.0f;

    const float* __restrict__ f0p = features + (size_t)r0 * C;
    const float* __restrict__ f1p = features + (size_t)r1 * C;
    const float* __restrict__ f2p = features + (size_t)r2 * C;
    const float* __restrict__ f3p = features + (size_t)r3 * C;

    float* __restrict__ og = out_grouped + (size_t)q * (C * NSAMPLE);
    #pragma unroll
    for (int k = 0; k < 8; ++k) {
        const int c = 8 * k + chi;
        float4 v;
        v.x = f0p[c] * k0;
        v.y = f1p[c] * k1;
        v.z = f2p[c] * k2;
        v.w = f3p[c] * k3;
        *reinterpret_cast<float4*>(og + (size_t)(k * 64 + lane) * 4) = v;
    }

    if (lane == 0) out_cnt[q] = (float)found;
}

extern "C" void kernel_launch(void* const* d_in, const int* in_sizes, int n_in,
                              void* d_out, int out_size, void* d_ws, size_t ws_size,
                              hipStream_t stream) {
    const float* xyz      = (const float*)d_in[0];
    const int*   xyz_cnt  = (const int*)d_in[1];
    const float* new_xyz  = (const float*)d_in[2];
    const int*   new_cnt  = (const int*)d_in[3];
    const float* features = (const float*)d_in[4];

    const int B = in_sizes[1];
    const int N = in_sizes[0] / 3;
    const int M = in_sizes[2] / 3;
    const int C = in_sizes[4] / N;   // 64

    float* out_grouped = (float*)d_out;
    float* out_cnt     = (float*)d_out + (size_t)M * C * NSAMPLE;

    dim3 grid((M + WPB - 1) / WPB), block(64 * WPB);
    const size_t need = (size_t)N * sizeof(float4);

    if (ws_size >= need) {
        float4* xyz4 = (float4*)d_ws;
        hipLaunchKernelGGL(pack_xyz_kernel, dim3((N + 255) / 256), dim3(256), 0, stream,
                           xyz, xyz4, N);
        hipLaunchKernelGGL((cube_query_group_kernel<true>), grid, block, 0, stream,
                           xyz, (const float4*)xyz4, xyz_cnt, new_xyz, new_cnt, features,
                           out_grouped, out_cnt, B, M, C);
    } else {
        hipLaunchKernelGGL((cube_query_group_kernel<false>), grid, block, 0, stream,
                           xyz, (const float4*)nullptr, xyz_cnt, new_xyz, new_cnt, features,
                           out_grouped, out_cnt, B, M, C);
    }
}

// Round 5
// 98.920 us; speedup vs baseline: 2.7834x; 1.0699x over previous
//
#include <hip/hip_runtime.h>

#define NSAMPLE 32
#define RX 0.1f
#define RY 0.1f
#define RZ 0.1f
#define QPW 4   // queries per wave (independent ballot chains -> ILP)
#define WPB 4   // waves per block

// Pre-pass: pack xyz (N,3) AoS -> float4 (x,y,z,0): one dwordx4 per point.
__global__ __launch_bounds__(256) void pack_xyz_kernel(
    const float* __restrict__ xyz, float4* __restrict__ xyz4, int N)
{
    const int i = blockIdx.x * blockDim.x + threadIdx.x;
    if (i < N) {
        float4 v;
        v.x = xyz[i * 3 + 0];
        v.y = xyz[i * 3 + 1];
        v.z = xyz[i * 3 + 2];
        v.w = 0.0f;
        xyz4[i] = v;
    }
}

// One wave scans for QPW=4 consecutive queries simultaneously:
//  - 256 points/chunk (4 float4 loads/lane), A/B register double buffer
//    (no copies; compiler emits counted vmcnt waits for the buffer in use)
//  - per query: max3(|dx|,|dy|,|dz|) < r test, ballot+mbcnt ordered slot
//    assignment, SGPR `found`, scalar early-skip once a query has 32.
//  - epilogue per query: direct gather (32B-coalesced) -> float4 stores.
template <bool PACKED>
__global__ __launch_bounds__(64 * WPB, 4) void cube_query_group_kernel(
    const float*  __restrict__ xyz,       // (N,3) AoS (!PACKED)
    const float4* __restrict__ xyz4,      // (N)    (PACKED)
    const int*    __restrict__ xyz_cnt,   // (B,)
    const float*  __restrict__ new_xyz,   // (M,3)
    const int*    __restrict__ new_cnt,   // (B,)
    const float*  __restrict__ features,  // (N,C) C=64
    float* __restrict__ out_grouped,      // (M,C,NSAMPLE)
    float* __restrict__ out_cnt,          // (M,)
    int B, int M, int C)
{
    const int wave = threadIdx.x >> 6;
    const int lane = threadIdx.x & 63;
    const int qbase = (blockIdx.x * WPB + wave) * QPW;
    if (qbase >= M) return;

    __shared__ int s_idx_all[WPB][QPW][NSAMPLE];
    int (*s_idx)[NSAMPLE] = s_idx_all[wave];
    {   // init all QPW*NSAMPLE = 128 slots to 0 (safe gather for empty slots)
        int* p = &s_idx[0][0];
        p[lane] = 0;
        p[lane + 64] = 0;
    }

    // ---- per-query batch info (B tiny; all values wave-uniform) ----
    int   xs[QPW], nbq[QPW], fnd[QPW];
    float qx[QPW], qy[QPW], qz[QPW];
    #pragma unroll
    for (int qi = 0; qi < QPW; ++qi) {
        const int q = qbase + qi;
        if (q < M) {
            int xstart = 0, qacc = 0, b = 0;
            for (int i = 0; i < B; ++i) {
                const int cnt = new_cnt[i];
                if (q < qacc + cnt) { b = i; break; }
                qacc += cnt; xstart += xyz_cnt[i];
            }
            xs[qi] = xstart; nbq[qi] = xyz_cnt[b];
            qx[qi] = new_xyz[q * 3 + 0];
            qy[qi] = new_xyz[q * 3 + 1];
            qz[qi] = new_xyz[q * 3 + 2];
            fnd[qi] = 0;
        } else {              // inactive: pretend done
            xs[qi] = xs[0]; nbq[qi] = nbq[0];
            qx[qi] = qx[0]; qy[qi] = qy[0]; qz[qi] = qz[0];
            fnd[qi] = NSAMPLE;
        }
    }
    bool uniform = true;
    #pragma unroll
    for (int qi = 1; qi < QPW; ++qi)
        uniform = uniform && (xs[qi] == xs[0]) && (nbq[qi] == nbq[0]);

    const unsigned long long lt = (1ull << lane) - 1ull;

    auto load_pt = [&](const float4* xp4, const float* xp, int p) -> float4 {
        if (PACKED) return xp4[p];
        float4 v;
        v.x = xp[p * 3 + 0]; v.y = xp[p * 3 + 1]; v.z = xp[p * 3 + 2]; v.w = 0.f;
        return v;
    };

    // test one 64-point group against all (unfinished) queries
    auto test_group = [&](const float4& v, int gpidx, bool inb) {
        #pragma unroll
        for (int qi = 0; qi < QPW; ++qi) {
            if (fnd[qi] >= NSAMPLE) continue;   // scalar branch (fnd is SGPR)
            const float m3 = fmaxf(fmaxf(fabsf(qx[qi] - v.x),
                                         fabsf(qy[qi] - v.y)),
                                   fabsf(qz[qi] - v.z));
            const bool c = inb & (m3 < RX);
            const unsigned long long m = __ballot(c);
            if (c) {
                const int slot = fnd[qi] + (int)__popcll(m & lt);
                if (slot < NSAMPLE) s_idx[qi][slot] = gpidx;
            }
            fnd[qi] += (int)__popcll(m);
        }
    };
    auto alldone = [&]() -> bool {
        return (fnd[0] >= NSAMPLE) & (fnd[1] >= NSAMPLE) &
               (fnd[2] >= NSAMPLE) & (fnd[3] >= NSAMPLE);
    };

    if (uniform) {
        const float4* __restrict__ xp4 = PACKED ? (xyz4 + xs[0]) : nullptr;
        const float*  __restrict__ xp  = PACKED ? nullptr : (xyz + (size_t)xs[0] * 3);
        const int nb    = nbq[0];
        const int nfull = nb & ~255;
        int base = 0;

        if (nfull > 0 && !alldone()) {
            float4 A[4], Bb[4];
            #pragma unroll
            for (int k = 0; k < 4; ++k) A[k] = load_pt(xp4, xp, k * 64 + lane);

            while (true) {
                int nxt = base + 256;
                if (nxt < nfull) {
                    #pragma unroll
                    for (int k = 0; k < 4; ++k) Bb[k] = load_pt(xp4, xp, nxt + k * 64 + lane);
                }
                #pragma unroll
                for (int k = 0; k < 4; ++k)
                    test_group(A[k], xs[0] + base + k * 64 + lane, true);
                base = nxt;
                if (alldone() || base >= nfull) break;

                nxt = base + 256;
                if (nxt < nfull) {
                    #pragma unroll
                    for (int k = 0; k < 4; ++k) A[k] = load_pt(xp4, xp, nxt + k * 64 + lane);
                }
                #pragma unroll
                for (int k = 0; k < 4; ++k)
                    test_group(Bb[k], xs[0] + base + k * 64 + lane, true);
                base = nxt;
                if (alldone() || base >= nfull) break;
            }
        }
        // masked tail (nb not a multiple of 256, or tiny nb)
        while (!alldone() && base < nb) {
            #pragma unroll
            for (int k = 0; k < 4; ++k) {
                const int p = base + k * 64 + lane;
                const bool inb = (p < nb);
                const float4 v = load_pt(xp4, xp, inb ? p : 0);
                test_group(v, xs[0] + p, inb);
            }
            base += 256;
        }
    } else {
        // rare: wave's queries span batches -> scan per query (simple masked loop)
        #pragma unroll
        for (int qi = 0; qi < QPW; ++qi) {
            const float4* __restrict__ xp4 = PACKED ? (xyz4 + xs[qi]) : nullptr;
            const float*  __restrict__ xp  = PACKED ? nullptr : (xyz + (size_t)xs[qi] * 3);
            const int nb = nbq[qi];
            for (int base = 0; base < nb && fnd[qi] < NSAMPLE; base += 64) {
                const int p = base + lane;
                const bool inb = (p < nb);
                const float4 v = load_pt(xp4, xp, inb ? p : 0);
                const float m3 = fmaxf(fmaxf(fabsf(qx[qi] - v.x),
                                             fabsf(qy[qi] - v.y)),
                                       fabsf(qz[qi] - v.z));
                const bool c = inb & (m3 < RX);
                const unsigned long long m = __ballot(c);
                if (c) {
                    const int slot = fnd[qi] + (int)__popcll(m & lt);
                    if (slot < NSAMPLE) s_idx[qi][slot] = xs[qi] + p;
                }
                fnd[qi] += (int)__popcll(m);
            }
        }
    }

    // all lanes' ds_writes must land before cross-lane reads (single wave:
    // fence the LDS queue + pin the schedule; no barrier needed)
    asm volatile("s_waitcnt lgkmcnt(0)" ::: "memory");
    __builtin_amdgcn_sched_barrier(0);

    // ---- epilogue: per query, direct gather + coalesced float4 stores ----
    // lane owns rows s0..s0+3 (s0=4*(lane&7)) and channels c = 8k+(lane>>3):
    // store t0=(k*64+lane)*4 -> c=t0>>5, s=t0&31 matches (c, s0..s0+3).
    const int s0  = 4 * (lane & 7);
    const int chi = lane >> 3;
    for (int qi = 0; qi < QPW; ++qi) {
        const int q = qbase + qi;
        if (q >= M) continue;
        const int found = fnd[qi] > NSAMPLE ? NSAMPLE : fnd[qi];
        const int r0 = s_idx[qi][s0 + 0];
        const int r1 = s_idx[qi][s0 + 1];
        const int r2 = s_idx[qi][s0 + 2];
        const int r3 = s_idx[qi][s0 + 3];
        const float k0 = (s0 + 0) < found ? 1.0f : 0.0f;
        const float k1 = (s0 + 1) < found ? 1.0f : 0.0f;
        const float k2 = (s0 + 2) < found ? 1.0f : 0.0f;
        const float k3 = (s0 + 3) < found ? 1.0f : 0.0f;

        const float* __restrict__ f0p = features + (size_t)r0 * C;
        const float* __restrict__ f1p = features + (size_t)r1 * C;
        const float* __restrict__ f2p = features + (size_t)r2 * C;
        const float* __restrict__ f3p = features + (size_t)r3 * C;

        float* __restrict__ og = out_grouped + (size_t)q * (C * NSAMPLE);
        #pragma unroll
        for (int k = 0; k < 8; ++k) {
            const int c = 8 * k + chi;
            float4 v;
            v.x = f0p[c] * k0;
            v.y = f1p[c] * k1;
            v.z = f2p[c] * k2;
            v.w = f3p[c] * k3;
            *reinterpret_cast<float4*>(og + (size_t)(k * 64 + lane) * 4) = v;
        }
        if (lane == 0) out_cnt[q] = (float)found;
    }
}

extern "C" void kernel_launch(void* const* d_in, const int* in_sizes, int n_in,
                              void* d_out, int out_size, void* d_ws, size_t ws_size,
                              hipStream_t stream) {
    const float* xyz      = (const float*)d_in[0];
    const int*   xyz_cnt  = (const int*)d_in[1];
    const float* new_xyz  = (const float*)d_in[2];
    const int*   new_cnt  = (const int*)d_in[3];
    const float* features = (const float*)d_in[4];

    const int B = in_sizes[1];
    const int N = in_sizes[0] / 3;
    const int M = in_sizes[2] / 3;
    const int C = in_sizes[4] / N;   // 64

    float* out_grouped = (float*)d_out;
    float* out_cnt     = (float*)d_out + (size_t)M * C * NSAMPLE;

    const int qpb = WPB * QPW;                      // 16 queries per block
    dim3 grid((M + qpb - 1) / qpb), block(64 * WPB);
    const size_t need = (size_t)N * sizeof(float4);

    if (ws_size >= need) {
        float4* xyz4 = (float4*)d_ws;
        hipLaunchKernelGGL(pack_xyz_kernel, dim3((N + 255) / 256), dim3(256), 0, stream,
                           xyz, xyz4, N);
        hipLaunchKernelGGL((cube_query_group_kernel<true>), grid, block, 0, stream,
                           xyz, (const float4*)xyz4, xyz_cnt, new_xyz, new_cnt, features,
                           out_grouped, out_cnt, B, M, C);
    } else {
        hipLaunchKernelGGL((cube_query_group_kernel<false>), grid, block, 0, stream,
                           xyz, (const float4*)nullptr, xyz_cnt, new_xyz, new_cnt, features,
                           out_grouped, out_cnt, B, M, C);
    }
}